// Round 8
// baseline (70.659 us; speedup 1.0000x reference)
//
#include <hip/hip_runtime.h>

// Problem constants
#define B_  32
#define L_  2048
#define D_  256
#define T_  64
#define KW  3
// 2 adjacent 16-row tiles per block (32 rows + 2 halo staged once)
#define XROWS 34

typedef float f32x4 __attribute__((ext_vector_type(4)));
typedef short s16x8 __attribute__((ext_vector_type(8)));
typedef short s16x4 __attribute__((ext_vector_type(4)));

__device__ __forceinline__ short f2bf(float f) {
    unsigned u = __builtin_bit_cast(unsigned, f);
    u += 0x7FFFu + ((u >> 16) & 1u);          // round-to-nearest-even
    return (short)(u >> 16);
}
__device__ __forceinline__ float bf2f(short s) {
    unsigned u = ((unsigned)(unsigned short)s) << 16;
    return __builtin_bit_cast(float, u);
}

// ---------------------------------------------------------------------------
// fused prep (one launch):
//  bx <  16 : CbfPk = bf16(C) packed in phase-1 B-fragment order
//             C[t][d] -> CbfPk[(((tt*8+ks)*4+g)*16+c)*8+e]
//  bx >= 16 : kc[n][t] = relu(b[n] + sum_dd C[t][dd]*W[dd][n]) packed in
//             phase-2 B-frag order: (n,t) -> kcPk[(((nb*2+ks)*4+g)*16+c)*8+e]
// ---------------------------------------------------------------------------
__global__ __launch_bounds__(256) void prep_kernel(const float* __restrict__ C,
                                                   const float* __restrict__ W,
                                                   const float* __restrict__ bias,
                                                   short* __restrict__ CbfPk,
                                                   short* __restrict__ kcPk) {
    __shared__ float Ws[256 * 16];
    const int tid = threadIdx.x;

    if (blockIdx.x < 16) {
        const int i0 = (blockIdx.x * 256 + tid) * 4;
        const int t = i0 >> 8, d = i0 & 255;
        const f32x4 v = *(const f32x4*)(C + i0);
        s16x4 s;
        s[0] = f2bf(v[0]); s[1] = f2bf(v[1]); s[2] = f2bf(v[2]); s[3] = f2bf(v[3]);
        const int tt = t >> 4, c = t & 15, ks = d >> 5, gg = (d >> 3) & 3, e = d & 7;
        *(s16x4*)&CbfPk[(((tt * 8 + ks) * 4 + gg) * 16 + c) * 8 + e] = s;
        return;
    }

    const int nb = blockIdx.x - 16;
    const int n0 = nb * 16;

    for (int idx = tid; idx < 256 * 16; idx += 256) {
        const int dd = idx >> 4, nl = idx & 15;
        Ws[idx] = W[dd * (KW * D_) + n0 + nl];
    }
    __syncthreads();

    const int t  = tid >> 2;
    const int nl = tid & 3;
    float acc[4];
    #pragma unroll
    for (int i = 0; i < 4; ++i) acc[i] = bias[n0 + nl + 4 * i];

    const float* Crow = C + t * D_;
    for (int dd = 0; dd < D_; ++dd) {
        const float cv = Crow[dd];
        #pragma unroll
        for (int i = 0; i < 4; ++i)
            acc[i] = fmaf(cv, Ws[dd * 16 + nl + 4 * i], acc[i]);
    }
    const int ks = t >> 5, gg = (t >> 3) & 3, e = t & 7;
    #pragma unroll
    for (int i = 0; i < 4; ++i) {
        const int cc = nl + 4 * i;
        kcPk[(((nb * 2 + ks) * 4 + gg) * 16 + cc) * 8 + e] = f2bf(fmaxf(acc[i], 0.f));
    }
}

// ---------------------------------------------------------------------------
#define XST 264
#define ATS 72

// phase-1 for one 16-row tile: att_tile = x_tile @ C^T (8 MFMA), atts in LDS.
// ro = 0 for tile0, 16 for tile1 (xs row k == x row l0a-1+k).
__device__ __forceinline__ void phase1(const short* xs, short* atts_t,
                                       const short* __restrict__ CbfPk,
                                       int w, int g, int c, int ro) {
    f32x4 acc = (f32x4){0.f, 0.f, 0.f, 0.f};
    const short* xr = &xs[(ro + 1 + c) * XST];
    #pragma unroll
    for (int ks = 0; ks < 8; ++ks) {
        const s16x8 cb = *(const s16x8*)&CbfPk[(((w * 8 + ks) * 4 + g) * 16 + c) * 8];
        const s16x8 a  = *(const s16x8*)&xr[ks * 32 + g * 8];
        acc = __builtin_amdgcn_mfma_f32_16x16x32_bf16(a, cb, acc, 0, 0, 0);
    }
    #pragma unroll
    for (int r = 0; r < 4; ++r)
        atts_t[(g * 4 + r) * ATS + w * 16 + c] = f2bf(acc[r]);
}

// phase-2 compute+fold+store for one tile within one dtl (B-frags shared).
__device__ __forceinline__ void ph2_tile(s16x8 af0, s16x8 af1,
                                         s16x8 b0, s16x8 b1, s16x8 b2,
                                         s16x8 b3, s16x8 b4, s16x8 b5,
                                         const short* xs, int ro,
                                         float* __restrict__ out, size_t outBase,
                                         int g, int c, int dcol) {
    f32x4 a0 = (f32x4){0.f,0.f,0.f,0.f};
    f32x4 a1 = (f32x4){0.f,0.f,0.f,0.f};
    f32x4 a2 = (f32x4){0.f,0.f,0.f,0.f};
    a0 = __builtin_amdgcn_mfma_f32_16x16x32_bf16(af0, b0, a0, 0, 0, 0);
    a0 = __builtin_amdgcn_mfma_f32_16x16x32_bf16(af1, b1, a0, 0, 0, 0);
    a1 = __builtin_amdgcn_mfma_f32_16x16x32_bf16(af0, b2, a1, 0, 0, 0);
    a1 = __builtin_amdgcn_mfma_f32_16x16x32_bf16(af1, b3, a1, 0, 0, 0);
    a2 = __builtin_amdgcn_mfma_f32_16x16x32_bf16(af0, b4, a2, 0, 0, 0);
    a2 = __builtin_amdgcn_mfma_f32_16x16x32_bf16(af1, b5, a2, 0, 0, 0);

    // window fold: out[l,d] = sum_j ki_j[l,d] * x[l-1+j,d]
    float xv[6];
    #pragma unroll
    for (int i = 0; i < 6; ++i)
        xv[i] = bf2f(xs[(ro + g * 4 + i) * XST + dcol]);

    #pragma unroll
    for (int r = 0; r < 4; ++r) {
        const float o = a0[r] * xv[r] + a1[r] * xv[r + 1] + a2[r] * xv[r + 2];
        out[outBase + (size_t)(ro + g * 4 + r) * D_ + dcol] = o;
    }
}

// ---------------------------------------------------------------------------
// main: per block = 32 rows (2 tiles of 16) of one batch, 4 waves.
//  LDS = xs[34][264] (18.0 KB) + atts0/atts1 (4.6 KB) = 22.6 KB -> 7 blocks/CU.
//  Schedule: issue loads A (rows 0-17) + B (rows 18-33) early; write A;
//  barrier; ph1(t0); write B (latency hidden); barrier; ph1(t1); barrier;
//  joint ph2 with B-fragments loaded ONCE for both tiles.
// ---------------------------------------------------------------------------
__global__ __launch_bounds__(256, 7) void main_kernel(const float* __restrict__ x,
                                                      const short* __restrict__ CbfPk,
                                                      const short* __restrict__ kcPk,
                                                      float* __restrict__ out) {
    __shared__ short xs[XROWS * XST];        // 17952 B
    __shared__ short atts0[16 * ATS];        //  2304 B
    __shared__ short atts1[16 * ATS];        //  2304 B

    const int tid  = threadIdx.x;
    const int w    = tid >> 6;
    const int lane = tid & 63;
    const int c    = lane & 15;
    const int g    = lane >> 4;
    const int l0a  = blockIdx.x * 32;        // tile0 rows l0a.., tile1 rows l0a+16..
    const int b    = blockIdx.y;

    const f32x4* x4 = (const f32x4*)(x + (size_t)b * L_ * D_);

    // ---- issue stage-A loads (xs rows 0..17 = x rows l0a-1 .. l0a+16) ----
    f32x4 rA[5];
    #pragma unroll
    for (int k = 0; k < 5; ++k) {
        const int idx = tid + k * 256;
        if (idx < 18 * 64) {
            const int l = l0a - 1 + (idx >> 6);
            rA[k] = (l >= 0 && l < L_) ? x4[(size_t)l * 64 + (idx & 63)]
                                       : (f32x4){0.f, 0.f, 0.f, 0.f};
        }
    }
    // ---- issue stage-B loads (xs rows 18..33 = x rows l0a+17 .. l0a+32) ----
    f32x4 rB[4];
    #pragma unroll
    for (int k = 0; k < 4; ++k) {
        const int idx = tid + k * 256;
        const int l = l0a + 17 + (idx >> 6);
        rB[k] = (l < L_) ? x4[(size_t)l * 64 + (idx & 63)]
                         : (f32x4){0.f, 0.f, 0.f, 0.f};
    }

    // ---- write stage A ----
    #pragma unroll
    for (int k = 0; k < 5; ++k) {
        const int idx = tid + k * 256;
        if (idx < 18 * 64) {
            s16x4 s;
            s[0] = f2bf(rA[k][0]); s[1] = f2bf(rA[k][1]);
            s[2] = f2bf(rA[k][2]); s[3] = f2bf(rA[k][3]);
            *(s16x4*)&xs[(idx >> 6) * XST + (idx & 63) * 4] = s;
        }
    }
    __syncthreads();                         // xs rows 0..17 ready

    phase1(xs, atts0, CbfPk, w, g, c, 0);

    // ---- write stage B (rB latency hidden under ph1 tile0) ----
    #pragma unroll
    for (int k = 0; k < 4; ++k) {
        const int idx = tid + k * 256;
        s16x4 s;
        s[0] = f2bf(rB[k][0]); s[1] = f2bf(rB[k][1]);
        s[2] = f2bf(rB[k][2]); s[3] = f2bf(rB[k][3]);
        *(s16x4*)&xs[(18 + (idx >> 6)) * XST + (idx & 63) * 4] = s;
    }
    __syncthreads();                         // atts0 + xs rows 18..33 ready

    phase1(xs, atts1, CbfPk, w, g, c, 16);
    __syncthreads();                         // atts1 ready

    // ---- joint phase 2: B-frags loaded once, used for both tiles ----
    const s16x8 af0a = *(const s16x8*)&atts0[c * ATS + 0 * 32 + g * 8];
    const s16x8 af1a = *(const s16x8*)&atts0[c * ATS + 1 * 32 + g * 8];
    const s16x8 af0b = *(const s16x8*)&atts1[c * ATS + 0 * 32 + g * 8];
    const s16x8 af1b = *(const s16x8*)&atts1[c * ATS + 1 * 32 + g * 8];

    const size_t outBase = ((size_t)b * L_ + l0a) * D_;

    #pragma unroll
    for (int dtl = 0; dtl < 4; ++dtl) {
        const int dcol = w * 64 + dtl * 16 + c;
        const int nbb  = w * 4 + dtl;        // nb = j*16 + nbb
        const s16x8 b0 = *(const s16x8*)&kcPk[((((0 * 16 + nbb) * 2 + 0) * 4 + g) * 16 + c) * 8];
        const s16x8 b1 = *(const s16x8*)&kcPk[((((0 * 16 + nbb) * 2 + 1) * 4 + g) * 16 + c) * 8];
        const s16x8 b2 = *(const s16x8*)&kcPk[((((1 * 16 + nbb) * 2 + 0) * 4 + g) * 16 + c) * 8];
        const s16x8 b3 = *(const s16x8*)&kcPk[((((1 * 16 + nbb) * 2 + 1) * 4 + g) * 16 + c) * 8];
        const s16x8 b4 = *(const s16x8*)&kcPk[((((2 * 16 + nbb) * 2 + 0) * 4 + g) * 16 + c) * 8];
        const s16x8 b5 = *(const s16x8*)&kcPk[((((2 * 16 + nbb) * 2 + 1) * 4 + g) * 16 + c) * 8];

        ph2_tile(af0a, af1a, b0, b1, b2, b3, b4, b5, xs, 0,  out, outBase, g, c, dcol);
        ph2_tile(af0b, af1b, b0, b1, b2, b3, b4, b5, xs, 16, out, outBase, g, c, dcol);
    }
}

// ---------------------------------------------------------------------------
extern "C" void kernel_launch(void* const* d_in, const int* in_sizes, int n_in,
                              void* d_out, int out_size, void* d_ws, size_t ws_size,
                              hipStream_t stream) {
    const float* x    = (const float*)d_in[0];
    const float* C    = (const float*)d_in[1];
    const float* Wden = (const float*)d_in[2];
    const float* bden = (const float*)d_in[3];
    float* out = (float*)d_out;

    short* kcPk  = (short*)d_ws;                   // [768][64] bf16 = 98304 B
    short* CbfPk = (short*)d_ws + KW * D_ * T_;    // [64][256] bf16 = 32768 B

    prep_kernel<<<dim3(64), dim3(256), 0, stream>>>(C, Wden, bden, CbfPk, kcPk);

    dim3 grid(L_ / 32, B_);
    main_kernel<<<grid, dim3(256), 0, stream>>>(x, CbfPk, kcPk, out);
}

// Round 9
// 57.479 us; speedup vs baseline: 1.2293x; 1.2293x over previous
//
#include <hip/hip_runtime.h>

// Problem constants
#define B_  32
#define L_  2048
#define D_  256
#define T_  64
#define KW  3

typedef float f32x4 __attribute__((ext_vector_type(4)));
typedef short s16x8 __attribute__((ext_vector_type(8)));
typedef short s16x4 __attribute__((ext_vector_type(4)));

__device__ __forceinline__ short f2bf(float f) {
    unsigned u = __builtin_bit_cast(unsigned, f);
    u += 0x7FFFu + ((u >> 16) & 1u);          // round-to-nearest-even
    return (short)(u >> 16);
}
__device__ __forceinline__ float bf2f(short s) {
    unsigned u = ((unsigned)(unsigned short)s) << 16;
    return __builtin_bit_cast(float, u);
}

// ---------------------------------------------------------------------------
// fused prep (one launch):
//  bx <  16 : CbfPk = bf16(C) packed in phase-1 B-fragment order
//  bx >= 16 : kcPk = packed relu(C@W+b) in phase-2 B-fragment order
// ---------------------------------------------------------------------------
__global__ __launch_bounds__(256) void prep_kernel(const float* __restrict__ C,
                                                   const float* __restrict__ W,
                                                   const float* __restrict__ bias,
                                                   short* __restrict__ CbfPk,
                                                   short* __restrict__ kcPk) {
    __shared__ float Ws[256 * 16];
    const int tid = threadIdx.x;

    if (blockIdx.x < 16) {
        const int i0 = (blockIdx.x * 256 + tid) * 4;
        const int t = i0 >> 8, d = i0 & 255;
        const f32x4 v = *(const f32x4*)(C + i0);
        s16x4 s;
        s[0] = f2bf(v[0]); s[1] = f2bf(v[1]); s[2] = f2bf(v[2]); s[3] = f2bf(v[3]);
        const int tt = t >> 4, c = t & 15, ks = d >> 5, gg = (d >> 3) & 3, e = d & 7;
        *(s16x4*)&CbfPk[(((tt * 8 + ks) * 4 + gg) * 16 + c) * 8 + e] = s;
        return;
    }

    const int nb = blockIdx.x - 16;
    const int n0 = nb * 16;

    for (int idx = tid; idx < 256 * 16; idx += 256) {
        const int dd = idx >> 4, nl = idx & 15;
        Ws[idx] = W[dd * (KW * D_) + n0 + nl];
    }
    __syncthreads();

    const int t  = tid >> 2;
    const int nl = tid & 3;
    float acc[4];
    #pragma unroll
    for (int i = 0; i < 4; ++i) acc[i] = bias[n0 + nl + 4 * i];

    const float* Crow = C + t * D_;
    for (int dd = 0; dd < D_; ++dd) {
        const float cv = Crow[dd];
        #pragma unroll
        for (int i = 0; i < 4; ++i)
            acc[i] = fmaf(cv, Ws[dd * 16 + nl + 4 * i], acc[i]);
    }
    const int ks = t >> 5, gg = (t >> 3) & 3, e = t & 7;
    #pragma unroll
    for (int i = 0; i < 4; ++i) {
        const int cc = nl + 4 * i;
        kcPk[(((nb * 2 + ks) * 4 + gg) * 16 + cc) * 8 + e] = f2bf(fmaxf(acc[i], 0.f));
    }
}

// ---------------------------------------------------------------------------
#define XST 264
#define ATS 72

// phase-1 for one 16-row tile buffer (rows 0..17, A row = 1+c)
__device__ __forceinline__ void ph1(const short* xs_t, short* atts_t,
                                    const short* __restrict__ CbfPk,
                                    int w, int g, int c) {
    f32x4 acc = (f32x4){0.f, 0.f, 0.f, 0.f};
    const short* xr = &xs_t[(1 + c) * XST];
    #pragma unroll
    for (int ks = 0; ks < 8; ++ks) {
        const s16x8 cb = *(const s16x8*)&CbfPk[(((w * 8 + ks) * 4 + g) * 16 + c) * 8];
        const s16x8 a  = *(const s16x8*)&xr[ks * 32 + g * 8];
        acc = __builtin_amdgcn_mfma_f32_16x16x32_bf16(a, cb, acc, 0, 0, 0);
    }
    #pragma unroll
    for (int r = 0; r < 4; ++r)
        atts_t[(g * 4 + r) * ATS + w * 16 + c] = f2bf(acc[r]);
}

// phase-2 for one tile: 4 d-tiles, B-frags from packed kcPk (L2)
__device__ __forceinline__ void ph2(const short* xs_t, const short* atts_t,
                                    const short* __restrict__ kcPk,
                                    float* __restrict__ out, size_t outBase,
                                    int w, int g, int c) {
    const s16x8 afr0 = *(const s16x8*)&atts_t[c * ATS + 0 * 32 + g * 8];
    const s16x8 afr1 = *(const s16x8*)&atts_t[c * ATS + 1 * 32 + g * 8];

    #pragma unroll
    for (int dtl = 0; dtl < 4; ++dtl) {
        const int dcol = w * 64 + dtl * 16 + c;
        const int nbb  = w * 4 + dtl;        // nb = j*16 + nbb
        const s16x8 b0 = *(const s16x8*)&kcPk[((((0 * 16 + nbb) * 2 + 0) * 4 + g) * 16 + c) * 8];
        const s16x8 b1 = *(const s16x8*)&kcPk[((((0 * 16 + nbb) * 2 + 1) * 4 + g) * 16 + c) * 8];
        const s16x8 b2 = *(const s16x8*)&kcPk[((((1 * 16 + nbb) * 2 + 0) * 4 + g) * 16 + c) * 8];
        const s16x8 b3 = *(const s16x8*)&kcPk[((((1 * 16 + nbb) * 2 + 1) * 4 + g) * 16 + c) * 8];
        const s16x8 b4 = *(const s16x8*)&kcPk[((((2 * 16 + nbb) * 2 + 0) * 4 + g) * 16 + c) * 8];
        const s16x8 b5 = *(const s16x8*)&kcPk[((((2 * 16 + nbb) * 2 + 1) * 4 + g) * 16 + c) * 8];

        f32x4 a0 = (f32x4){0.f,0.f,0.f,0.f};
        f32x4 a1 = (f32x4){0.f,0.f,0.f,0.f};
        f32x4 a2 = (f32x4){0.f,0.f,0.f,0.f};
        a0 = __builtin_amdgcn_mfma_f32_16x16x32_bf16(afr0, b0, a0, 0, 0, 0);
        a0 = __builtin_amdgcn_mfma_f32_16x16x32_bf16(afr1, b1, a0, 0, 0, 0);
        a1 = __builtin_amdgcn_mfma_f32_16x16x32_bf16(afr0, b2, a1, 0, 0, 0);
        a1 = __builtin_amdgcn_mfma_f32_16x16x32_bf16(afr1, b3, a1, 0, 0, 0);
        a2 = __builtin_amdgcn_mfma_f32_16x16x32_bf16(afr0, b4, a2, 0, 0, 0);
        a2 = __builtin_amdgcn_mfma_f32_16x16x32_bf16(afr1, b5, a2, 0, 0, 0);

        // window fold: out[l,d] = sum_j ki_j[l,d] * x[l-1+j,d]; xs row 0 = l-1
        float xv[6];
        #pragma unroll
        for (int i = 0; i < 6; ++i)
            xv[i] = bf2f(xs_t[(g * 4 + i) * XST + dcol]);

        #pragma unroll
        for (int r = 0; r < 4; ++r) {
            const float o = a0[r] * xv[r] + a1[r] * xv[r + 1] + a2[r] * xv[r + 2];
            out[outBase + (size_t)(g * 4 + r) * D_ + dcol] = o;
        }
    }
}

// ---------------------------------------------------------------------------
// main: per block = 2 sequential 16-row tiles (l0, l0+16) of one batch.
//  Double LDS buffers; tile1's global loads are issued before the first
//  barrier so their HBM latency hides under ph1(T0); 3 barriers / 2 tiles.
//  LDS = 2*(18*264 + 16*72)*2B = 23.6 KB -> 6 blocks/CU.
// ---------------------------------------------------------------------------
__global__ __launch_bounds__(256, 6) void main_kernel(const float* __restrict__ x,
                                                      const short* __restrict__ CbfPk,
                                                      const short* __restrict__ kcPk,
                                                      float* __restrict__ out) {
    __shared__ short xs0[18 * XST];
    __shared__ short xs1[18 * XST];
    __shared__ short atts0[16 * ATS];
    __shared__ short atts1[16 * ATS];

    const int tid  = threadIdx.x;
    const int w    = tid >> 6;
    const int lane = tid & 63;
    const int c    = lane & 15;
    const int g    = lane >> 4;
    const int l0   = blockIdx.x * 32;        // tile0: l0, tile1: l0+16
    const int b    = blockIdx.y;

    const f32x4* x4 = (const f32x4*)(x + (size_t)b * L_ * D_);

    const int row  = tid >> 6;               // 0..3 (4 rows per pass)
    const int d4   = tid & 63;

    // ---- issue + write tile0 (xs0 rows 0..17 = x rows l0-1 .. l0+16) ----
    #pragma unroll
    for (int k = 0; k < 5; ++k) {
        const int rr = row + k * 4;
        if (rr < 18) {
            const int l = l0 - 1 + rr;
            f32x4 v = (l >= 0 && l < L_) ? x4[(size_t)l * 64 + d4]
                                         : (f32x4){0.f, 0.f, 0.f, 0.f};
            s16x4 s;
            s[0] = f2bf(v[0]); s[1] = f2bf(v[1]); s[2] = f2bf(v[2]); s[3] = f2bf(v[3]);
            *(s16x4*)&xs0[rr * XST + d4 * 4] = s;
        }
    }

    // ---- issue tile1 loads (xs1 rows 0..17 = x rows l0+15 .. l0+32) ----
    f32x4 rB0, rB1, rB2, rB3, rB4;
    {
        const int l = l0 + 15 + row;
        rB0 = (l < L_) ? x4[(size_t)(l +  0) * 64 + d4] : (f32x4){0.f,0.f,0.f,0.f};
        rB1 = (l +  4 < L_) ? x4[(size_t)(l +  4) * 64 + d4] : (f32x4){0.f,0.f,0.f,0.f};
        rB2 = (l +  8 < L_) ? x4[(size_t)(l +  8) * 64 + d4] : (f32x4){0.f,0.f,0.f,0.f};
        rB3 = (l + 12 < L_) ? x4[(size_t)(l + 12) * 64 + d4] : (f32x4){0.f,0.f,0.f,0.f};
        rB4 = (row < 2 && l + 16 < L_) ? x4[(size_t)(l + 16) * 64 + d4] : (f32x4){0.f,0.f,0.f,0.f};
    }

    __syncthreads();                         // xs0 ready; rB* in flight

    ph1(xs0, atts0, CbfPk, w, g, c);

    // ---- write tile1 (waits only on rB*) ----
    {
        s16x4 s;
        s[0]=f2bf(rB0[0]); s[1]=f2bf(rB0[1]); s[2]=f2bf(rB0[2]); s[3]=f2bf(rB0[3]);
        *(s16x4*)&xs1[(row +  0) * XST + d4 * 4] = s;
        s[0]=f2bf(rB1[0]); s[1]=f2bf(rB1[1]); s[2]=f2bf(rB1[2]); s[3]=f2bf(rB1[3]);
        *(s16x4*)&xs1[(row +  4) * XST + d4 * 4] = s;
        s[0]=f2bf(rB2[0]); s[1]=f2bf(rB2[1]); s[2]=f2bf(rB2[2]); s[3]=f2bf(rB2[3]);
        *(s16x4*)&xs1[(row +  8) * XST + d4 * 4] = s;
        s[0]=f2bf(rB3[0]); s[1]=f2bf(rB3[1]); s[2]=f2bf(rB3[2]); s[3]=f2bf(rB3[3]);
        *(s16x4*)&xs1[(row + 12) * XST + d4 * 4] = s;
        if (row < 2) {
            s[0]=f2bf(rB4[0]); s[1]=f2bf(rB4[1]); s[2]=f2bf(rB4[2]); s[3]=f2bf(rB4[3]);
            *(s16x4*)&xs1[(row + 16) * XST + d4 * 4] = s;
        }
    }

    __syncthreads();                         // atts0 + xs1 ready

    const size_t outBase0 = ((size_t)b * L_ + l0) * D_;
    ph2(xs0, atts0, kcPk, out, outBase0, w, g, c);

    ph1(xs1, atts1, CbfPk, w, g, c);
    __syncthreads();                         // atts1 ready

    const size_t outBase1 = ((size_t)b * L_ + l0 + 16) * D_;
    ph2(xs1, atts1, kcPk, out, outBase1, w, g, c);
}

// ---------------------------------------------------------------------------
extern "C" void kernel_launch(void* const* d_in, const int* in_sizes, int n_in,
                              void* d_out, int out_size, void* d_ws, size_t ws_size,
                              hipStream_t stream) {
    const float* x    = (const float*)d_in[0];
    const float* C    = (const float*)d_in[1];
    const float* Wden = (const float*)d_in[2];
    const float* bden = (const float*)d_in[3];
    float* out = (float*)d_out;

    short* kcPk  = (short*)d_ws;                   // [768][64] bf16 = 98304 B
    short* CbfPk = (short*)d_ws + KW * D_ * T_;    // [64][256] bf16 = 32768 B

    prep_kernel<<<dim3(64), dim3(256), 0, stream>>>(C, Wden, bden, CbfPk, kcPk);

    dim3 grid(L_ / 32, B_);
    main_kernel<<<grid, dim3(256), 0, stream>>>(x, CbfPk, kcPk, out);
}

// Round 10
// 49.091 us; speedup vs baseline: 1.4393x; 1.1709x over previous
//
#include <hip/hip_runtime.h>

// Problem constants
#define B_  32
#define L_  2048
#define D_  256
#define T_  64
#define KW  3

typedef float f32x4 __attribute__((ext_vector_type(4)));
typedef short s16x8 __attribute__((ext_vector_type(8)));
typedef short s16x4 __attribute__((ext_vector_type(4)));

__device__ __forceinline__ short f2bf(float f) {
    unsigned u = __builtin_bit_cast(unsigned, f);
    u += 0x7FFFu + ((u >> 16) & 1u);          // round-to-nearest-even
    return (short)(u >> 16);
}

// ---------------------------------------------------------------------------
// fused prep (one launch):
//  bx <  16 : CbfPk = bf16(C) packed in phase-1 B-fragment order
//  bx >= 16 : kcPk = packed relu(C@W+b) in phase-2 B-fragment order
// ---------------------------------------------------------------------------
__global__ __launch_bounds__(256) void prep_kernel(const float* __restrict__ C,
                                                   const float* __restrict__ W,
                                                   const float* __restrict__ bias,
                                                   short* __restrict__ CbfPk,
                                                   short* __restrict__ kcPk) {
    __shared__ float Ws[256 * 16];
    const int tid = threadIdx.x;

    if (blockIdx.x < 16) {
        const int i0 = (blockIdx.x * 256 + tid) * 4;
        const int t = i0 >> 8, d = i0 & 255;
        const f32x4 v = *(const f32x4*)(C + i0);
        s16x4 s;
        s[0] = f2bf(v[0]); s[1] = f2bf(v[1]); s[2] = f2bf(v[2]); s[3] = f2bf(v[3]);
        const int tt = t >> 4, c = t & 15, ks = d >> 5, gg = (d >> 3) & 3, e = d & 7;
        *(s16x4*)&CbfPk[(((tt * 8 + ks) * 4 + gg) * 16 + c) * 8 + e] = s;
        return;
    }

    const int nb = blockIdx.x - 16;
    const int n0 = nb * 16;

    for (int idx = tid; idx < 256 * 16; idx += 256) {
        const int dd = idx >> 4, nl = idx & 15;
        Ws[idx] = W[dd * (KW * D_) + n0 + nl];
    }
    __syncthreads();

    const int t  = tid >> 2;
    const int nl = tid & 3;
    float acc[4];
    #pragma unroll
    for (int i = 0; i < 4; ++i) acc[i] = bias[n0 + nl + 4 * i];

    const float* Crow = C + t * D_;
    for (int dd = 0; dd < D_; ++dd) {
        const float cv = Crow[dd];
        #pragma unroll
        for (int i = 0; i < 4; ++i)
            acc[i] = fmaf(cv, Ws[dd * 16 + nl + 4 * i], acc[i]);
    }
    const int ks = t >> 5, gg = (t >> 3) & 3, e = t & 7;
    #pragma unroll
    for (int i = 0; i < 4; ++i) {
        const int cc = nl + 4 * i;
        kcPk[(((nb * 2 + ks) * 4 + gg) * 16 + cc) * 8 + e] = f2bf(fmaxf(acc[i], 0.f));
    }
}

// ---------------------------------------------------------------------------
// main: per block = 16 rows of one batch, 4 waves.
//  x staged as RAW FP32 via global_load_lds (async DMA: no staging VALU, no
//  VGPR round-trip, loads stay in flight until the barrier's vmcnt(0)).
//  LDS: xsf[18][268] f32 (19.3 KB) + atts[16][72] bf16 (2.3 KB) -> 7 blk/CU.
//  phase1: att[16][64] via MFMA (x->bf16 cvt at fragment read).
//  phase2: wave w owns d in [w*64, w*64+64); B-frags from packed kcPk (L2);
//          3-tap window fold reads fp32 xs; fp32 store.
// ---------------------------------------------------------------------------
#define XSTF 268          // floats per xs row (256 data + 12 pad; 12 mod 32 banks)
#define ATS 72

__device__ __forceinline__ s16x8 cvt8(const float* p) {
    s16x8 r;
    #pragma unroll
    for (int i = 0; i < 8; ++i) r[i] = f2bf(p[i]);
    return r;
}

__global__ __launch_bounds__(256, 8) void main_kernel(const float* __restrict__ x,
                                                      const short* __restrict__ CbfPk,
                                                      const short* __restrict__ kcPk,
                                                      float* __restrict__ out) {
    __shared__ float xsf[18 * XSTF];       // 19296 B
    __shared__ short atts[16 * ATS];       //  2304 B

    const int tid  = threadIdx.x;
    const int w    = tid >> 6;        // wave 0..3
    const int lane = tid & 63;
    const int c    = lane & 15;
    const int g    = lane >> 4;
    const int l0   = blockIdx.x * 16;
    const int b    = blockIdx.y;

    const float* xb = x + (size_t)b * L_ * D_;

    // ---- stage x rows l0-1 .. l0+16 via async DMA (wave-uniform rows) ----
    #pragma unroll
    for (int k = 0; k < 5; ++k) {
        const int row = w + k * 4;
        if (row < 18) {
            const int l = l0 - 1 + row;
            float* ldsrow = &xsf[row * XSTF];
            if (l >= 0 && l < L_) {
                const float* gsrc = xb + (size_t)l * D_ + lane * 4;
                __builtin_amdgcn_global_load_lds(
                    (const __attribute__((address_space(1))) void*)gsrc,
                    (__attribute__((address_space(3))) void*)ldsrow,
                    16, 0, 0);
            } else {
                *(f32x4*)&ldsrow[lane * 4] = (f32x4){0.f, 0.f, 0.f, 0.f};
            }
        }
    }
    __syncthreads();   // vmcnt(0) drains the DMA; xsf ready

    // ---- phase 1: wave w computes all 16 rows x t-tile w ----
    {
        f32x4 acc = (f32x4){0.f, 0.f, 0.f, 0.f};
        const float* xr = &xsf[(1 + c) * XSTF];
        #pragma unroll
        for (int ks = 0; ks < 8; ++ks) {
            const s16x8 cb = *(const s16x8*)&CbfPk[(((w * 8 + ks) * 4 + g) * 16 + c) * 8];
            const s16x8 a  = cvt8(&xr[ks * 32 + g * 8]);
            acc = __builtin_amdgcn_mfma_f32_16x16x32_bf16(a, cb, acc, 0, 0, 0);
        }
        // D layout: col=lane&15 (t), row=(lane>>4)*4+reg (l)
        #pragma unroll
        for (int r = 0; r < 4; ++r)
            atts[(g * 4 + r) * ATS + w * 16 + c] = f2bf(acc[r]);
    }
    __syncthreads();

    // ---- phase 2 ----
    const s16x8 afr0 = *(const s16x8*)&atts[c * ATS + 0 * 32 + g * 8];
    const s16x8 afr1 = *(const s16x8*)&atts[c * ATS + 1 * 32 + g * 8];

    const size_t outBase = ((size_t)b * L_ + l0) * D_;

    #pragma unroll
    for (int dtl = 0; dtl < 4; ++dtl) {
        const int dcol = w * 64 + dtl * 16 + c;
        const int nbb  = w * 4 + dtl;        // nb = j*16 + nbb
        const s16x8 b0 = *(const s16x8*)&kcPk[((((0 * 16 + nbb) * 2 + 0) * 4 + g) * 16 + c) * 8];
        const s16x8 b1 = *(const s16x8*)&kcPk[((((0 * 16 + nbb) * 2 + 1) * 4 + g) * 16 + c) * 8];
        const s16x8 b2 = *(const s16x8*)&kcPk[((((1 * 16 + nbb) * 2 + 0) * 4 + g) * 16 + c) * 8];
        const s16x8 b3 = *(const s16x8*)&kcPk[((((1 * 16 + nbb) * 2 + 1) * 4 + g) * 16 + c) * 8];
        const s16x8 b4 = *(const s16x8*)&kcPk[((((2 * 16 + nbb) * 2 + 0) * 4 + g) * 16 + c) * 8];
        const s16x8 b5 = *(const s16x8*)&kcPk[((((2 * 16 + nbb) * 2 + 1) * 4 + g) * 16 + c) * 8];

        f32x4 a0 = (f32x4){0.f,0.f,0.f,0.f};
        f32x4 a1 = (f32x4){0.f,0.f,0.f,0.f};
        f32x4 a2 = (f32x4){0.f,0.f,0.f,0.f};
        a0 = __builtin_amdgcn_mfma_f32_16x16x32_bf16(afr0, b0, a0, 0, 0, 0);
        a0 = __builtin_amdgcn_mfma_f32_16x16x32_bf16(afr1, b1, a0, 0, 0, 0);
        a1 = __builtin_amdgcn_mfma_f32_16x16x32_bf16(afr0, b2, a1, 0, 0, 0);
        a1 = __builtin_amdgcn_mfma_f32_16x16x32_bf16(afr1, b3, a1, 0, 0, 0);
        a2 = __builtin_amdgcn_mfma_f32_16x16x32_bf16(afr0, b4, a2, 0, 0, 0);
        a2 = __builtin_amdgcn_mfma_f32_16x16x32_bf16(afr1, b5, a2, 0, 0, 0);

        // window fold: out[l,d] = sum_j ki_j[l,d] * x[l-1+j,d]; xsf row 0 = l0-1
        float xv[6];
        #pragma unroll
        for (int i = 0; i < 6; ++i)
            xv[i] = xsf[(g * 4 + i) * XSTF + dcol];

        #pragma unroll
        for (int r = 0; r < 4; ++r) {
            const float o = a0[r] * xv[r] + a1[r] * xv[r + 1] + a2[r] * xv[r + 2];
            out[outBase + (size_t)(g * 4 + r) * D_ + dcol] = o;
        }
    }
}

// ---------------------------------------------------------------------------
extern "C" void kernel_launch(void* const* d_in, const int* in_sizes, int n_in,
                              void* d_out, int out_size, void* d_ws, size_t ws_size,
                              hipStream_t stream) {
    const float* x    = (const float*)d_in[0];
    const float* C    = (const float*)d_in[1];
    const float* Wden = (const float*)d_in[2];
    const float* bden = (const float*)d_in[3];
    float* out = (float*)d_out;

    short* kcPk  = (short*)d_ws;                   // [768][64] bf16 = 98304 B
    short* CbfPk = (short*)d_ws + KW * D_ * T_;    // [64][256] bf16 = 32768 B

    prep_kernel<<<dim3(64), dim3(256), 0, stream>>>(C, Wden, bden, CbfPk, kcPk);

    dim3 grid(L_ / 16, B_);
    main_kernel<<<grid, dim3(256), 0, stream>>>(x, CbfPk, kcPk, out);
}